// Round 1
// baseline (2009.070 us; speedup 1.0000x reference)
//
#include <hip/hip_runtime.h>
#include <hip/hip_bf16.h>

// Problem constants (verified against in_sizes at launch where cheap)
#define DD   64      // feature dim
#define NL   5       // layers
#define NT   37      // classes
#define LD   (NL*DD) // 320

// ---------------------------------------------------------------------------
// CSR build: degree histogram
__global__ void deg_kernel(const int* __restrict__ dst, int* __restrict__ deg, int E) {
    int e = blockIdx.x * blockDim.x + threadIdx.x;
    if (e < E) atomicAdd(&deg[dst[e]], 1);
}

// Single-block exclusive scan (N up to ~1M). 1024 threads, 4 elems/thread.
__global__ void scan_kernel(const int* __restrict__ deg, int* __restrict__ rowptr,
                            int* __restrict__ cursor, int n) {
    __shared__ int sm[1024];
    int tid = threadIdx.x;
    int run = 0;
    const int CH = 4096;
    for (int base = 0; base < n; base += CH) {
        int i0 = base + tid * 4;
        int v0 = (i0 + 0 < n) ? deg[i0 + 0] : 0;
        int v1 = (i0 + 1 < n) ? deg[i0 + 1] : 0;
        int v2 = (i0 + 2 < n) ? deg[i0 + 2] : 0;
        int v3 = (i0 + 3 < n) ? deg[i0 + 3] : 0;
        int s = v0 + v1 + v2 + v3;
        sm[tid] = s;
        __syncthreads();
        for (int off = 1; off < 1024; off <<= 1) {
            int t = (tid >= off) ? sm[tid - off] : 0;
            __syncthreads();
            sm[tid] += t;
            __syncthreads();
        }
        int excl = sm[tid] - s;     // exclusive prefix of this thread within chunk
        int total = sm[1023];
        int p = run + excl;
        if (i0 + 0 < n) { rowptr[i0 + 0] = p; cursor[i0 + 0] = p; } p += v0;
        if (i0 + 1 < n) { rowptr[i0 + 1] = p; cursor[i0 + 1] = p; } p += v1;
        if (i0 + 2 < n) { rowptr[i0 + 2] = p; cursor[i0 + 2] = p; } p += v2;
        if (i0 + 3 < n) { rowptr[i0 + 3] = p; cursor[i0 + 3] = p; }
        run += total;
        __syncthreads();   // protect sm before next chunk overwrite
    }
    if (tid == 0) rowptr[n] = run;
}

// Fill CSR buckets with edge ids
__global__ void fill_kernel(const int* __restrict__ dst, int* __restrict__ cursor,
                            int* __restrict__ col, int E) {
    int e = blockIdx.x * blockDim.x + threadIdx.x;
    if (e < E) {
        int p = atomicAdd(&cursor[dst[e]], 1);
        col[p] = e;
    }
}

// ---------------------------------------------------------------------------
// Aggregation: one wave per node (lane = feature). Fuses edge encoder:
//   emb(e,l) = b_edge[l] + sum_k edge_attr[e][k] * W_edge[k][l]
//   u[v][l]  = (1+eps)*h[v][l] + sum_{e in CSR[v]} relu(h[src[e]][l] + emb(e,l))
__global__ void agg_kernel(const float* __restrict__ h, const float* __restrict__ ea,
                           const int* __restrict__ src, const int* __restrict__ rowptr,
                           const int* __restrict__ col, const float* __restrict__ W_edge,
                           const float* __restrict__ b_edge, const float* __restrict__ eps,
                           int layer, float* __restrict__ u, int n) {
    int v = blockIdx.x * 4 + (threadIdx.x >> 6);
    int l = threadIdx.x & 63;
    if (v >= n) return;
    float w[7];
#pragma unroll
    for (int k = 0; k < 7; ++k) w[k] = W_edge[k * DD + l];
    float be = b_edge[l];
    float acc = 0.f;
    int beg = rowptr[v], end = rowptr[v + 1];
    for (int idx = beg; idx < end; ++idx) {
        int e = col[idx];
        int s = src[e];
        float hv = h[s * DD + l];
        const float* eap = ea + e * 7;
        float emb = be;
#pragma unroll
        for (int k = 0; k < 7; ++k) emb += eap[k] * w[k];
        float m = hv + emb;
        acc += (m > 0.f) ? m : 0.f;
    }
    float ope = 1.0f + eps[layer];
    u[v * DD + l] = ope * h[v * DD + l] + acc;
}

// ---------------------------------------------------------------------------
// MLP: h_out = relu(u @ W + b), tiled 64 nodes/block, W in LDS.
__global__ void mlp_kernel(const float* __restrict__ u, const float* __restrict__ W,
                           const float* __restrict__ b, float* __restrict__ h_out, int n) {
    __shared__ float uS[64][DD];
    __shared__ float wS[DD][DD];
    int tid = threadIdx.x;            // 256
    int nodeBase = blockIdx.x * 64;
    for (int i = tid; i < DD * DD; i += 256) wS[i >> 6][i & 63] = W[i];
    for (int i = tid; i < 64 * DD; i += 256) {
        int node = nodeBase + (i >> 6);
        uS[i >> 6][i & 63] = (node < n) ? u[node * DD + (i & 63)] : 0.f;
    }
    __syncthreads();
    int j = tid & 63;
    int g = tid >> 6;                 // 0..3, each handles 16 nodes
    float bj = b[j];
    for (int nn = g * 16; nn < g * 16 + 16; ++nn) {
        float acc = bj;
#pragma unroll 8
        for (int l = 0; l < DD; ++l) acc += uS[nn][l] * wS[l][j];
        int node = nodeBase + nn;
        if (node < n) h_out[node * DD + j] = (acc > 0.f) ? acc : 0.f;
    }
}

// ---------------------------------------------------------------------------
// Per-layer mean-pool partial: batch is sorted, so a wave owns 64 consecutive
// nodes and flushes one atomic per graph transition.
__global__ void pool_kernel(const float* __restrict__ h, const int* __restrict__ batch,
                            float* __restrict__ g_sum, int layer, int n) {
    int wave = (blockIdx.x * blockDim.x + threadIdx.x) >> 6;
    int l = threadIdx.x & 63;
    int v0 = wave * 64;
    if (v0 >= n) return;
    int vend = min(v0 + 64, n);
    int cur = batch[v0];
    float acc = 0.f;
    for (int v = v0; v < vend; ++v) {
        int bv = batch[v];
        if (bv != cur) {
            atomicAdd(&g_sum[cur * LD + layer * DD + l], acc);
            acc = 0.f;
            cur = bv;
        }
        acc += h[v * DD + l];
    }
    atomicAdd(&g_sum[cur * LD + layer * DD + l], acc);
}

__global__ void cnt_kernel(const int* __restrict__ batch, int* __restrict__ cnt, int n) {
    int v = blockIdx.x * blockDim.x + threadIdx.x;
    if (v < n) atomicAdd(&cnt[batch[v]], 1);
}

// Readout: out[g][t] = b_pred[t] + sum_k (g_sum[g][k]/max(cnt,1)) * W_pred[k][t]
__global__ void readout_kernel(const float* __restrict__ g_sum, const int* __restrict__ cnt,
                               const float* __restrict__ W_pred, const float* __restrict__ b_pred,
                               float* __restrict__ out, int G) {
    int id = blockIdx.x * blockDim.x + threadIdx.x;
    if (id >= G * NT) return;
    int g = id / NT, t = id % NT;
    float c = (float)cnt[g];
    if (c < 1.f) c = 1.f;
    float inv = 1.f / c;
    float acc = b_pred[t];
    const float* gs = g_sum + g * LD;
    for (int k = 0; k < LD; ++k) acc += gs[k] * inv * W_pred[k * NT + t];
    out[id] = acc;
}

// ---------------------------------------------------------------------------
extern "C" void kernel_launch(void* const* d_in, const int* in_sizes, int n_in,
                              void* d_out, int out_size, void* d_ws, size_t ws_size,
                              hipStream_t stream) {
    const float* x       = (const float*)d_in[0];
    const int*   eidx    = (const int*)d_in[1];
    const float* ea      = (const float*)d_in[2];
    const int*   batch   = (const int*)d_in[3];
    const float* W_edge  = (const float*)d_in[4];
    const float* b_edge  = (const float*)d_in[5];
    const float* eps     = (const float*)d_in[6];
    const float* W_mlp   = (const float*)d_in[7];
    const float* b_mlp   = (const float*)d_in[8];
    const float* W_pred  = (const float*)d_in[9];
    const float* b_pred  = (const float*)d_in[10];
    float* out = (float*)d_out;

    const int N = in_sizes[3];          // 100000
    const int E = in_sizes[2] / 7;      // 1250000
    const int G = out_size / NT;        // 128
    const int* src = eidx;              // edge_index[0]
    const int* dst = eidx + E;          // edge_index[1]

    // workspace layout
    char* w = (char*)d_ws;
    float* u      = (float*)w;                 w += (size_t)N * DD * 4;
    float* hA     = (float*)w;                 w += (size_t)N * DD * 4;
    int*   deg    = (int*)w;                   w += (size_t)N * 4;
    int*   rowptr = (int*)w;                   w += (size_t)(N + 1) * 4;
    int*   cursor = (int*)w;                   w += (size_t)N * 4;
    int*   col    = (int*)w;                   w += (size_t)E * 4;
    float* g_sum  = (float*)w;                 w += (size_t)G * LD * 4;
    int*   cnt    = (int*)w;                   w += (size_t)G * 4;

    hipMemsetAsync(deg, 0, (size_t)N * 4, stream);
    hipMemsetAsync(g_sum, 0, (size_t)G * LD * 4, stream);
    hipMemsetAsync(cnt, 0, (size_t)G * 4, stream);

    // CSR build (once per launch; shared by all 5 layers)
    deg_kernel<<<(E + 255) / 256, 256, 0, stream>>>(dst, deg, E);
    scan_kernel<<<1, 1024, 0, stream>>>(deg, rowptr, cursor, N);
    fill_kernel<<<(E + 255) / 256, 256, 0, stream>>>(dst, cursor, col, E);

    cnt_kernel<<<(N + 255) / 256, 256, 0, stream>>>(batch, cnt, N);

    const float* h_cur = x;
    int aggBlocks  = (N + 3) / 4;
    int mlpBlocks  = (N + 63) / 64;
    int poolThreads = ((N + 63) / 64) * 64;
    int poolBlocks = (poolThreads + 255) / 256;
    for (int i = 0; i < NL; ++i) {
        agg_kernel<<<aggBlocks, 256, 0, stream>>>(h_cur, ea, src, rowptr, col,
                                                  W_edge, b_edge, eps, i, u, N);
        mlp_kernel<<<mlpBlocks, 256, 0, stream>>>(u, W_mlp + (size_t)i * DD * DD,
                                                  b_mlp + (size_t)i * DD, hA, N);
        pool_kernel<<<poolBlocks, 256, 0, stream>>>(hA, batch, g_sum, i, N);
        h_cur = hA;
    }

    readout_kernel<<<(G * NT + 255) / 256, 256, 0, stream>>>(g_sum, cnt, W_pred, b_pred, out, G);
}

// Round 2
// 1513.280 us; speedup vs baseline: 1.3276x; 1.3276x over previous
//
#include <hip/hip_runtime.h>
#include <hip/hip_bf16.h>

// Problem constants
#define DD   64      // feature dim
#define NL   5       // layers
#define NT   37      // classes
#define LD   (NL*DD) // 320

// ---------------------------------------------------------------------------
// CSR build: degree histogram
__global__ void deg_kernel(const int* __restrict__ dst, int* __restrict__ deg, int E) {
    int e = blockIdx.x * blockDim.x + threadIdx.x;
    if (e < E) atomicAdd(&deg[dst[e]], 1);
}

// Single-block exclusive scan. 1024 threads, 4 elems/thread.
__global__ void scan_kernel(const int* __restrict__ deg, int* __restrict__ rowptr,
                            int* __restrict__ cursor, int n) {
    __shared__ int sm[1024];
    int tid = threadIdx.x;
    int run = 0;
    const int CH = 4096;
    for (int base = 0; base < n; base += CH) {
        int i0 = base + tid * 4;
        int v0 = (i0 + 0 < n) ? deg[i0 + 0] : 0;
        int v1 = (i0 + 1 < n) ? deg[i0 + 1] : 0;
        int v2 = (i0 + 2 < n) ? deg[i0 + 2] : 0;
        int v3 = (i0 + 3 < n) ? deg[i0 + 3] : 0;
        int s = v0 + v1 + v2 + v3;
        sm[tid] = s;
        __syncthreads();
        for (int off = 1; off < 1024; off <<= 1) {
            int t = (tid >= off) ? sm[tid - off] : 0;
            __syncthreads();
            sm[tid] += t;
            __syncthreads();
        }
        int excl = sm[tid] - s;
        int total = sm[1023];
        int p = run + excl;
        if (i0 + 0 < n) { rowptr[i0 + 0] = p; cursor[i0 + 0] = p; } p += v0;
        if (i0 + 1 < n) { rowptr[i0 + 1] = p; cursor[i0 + 1] = p; } p += v1;
        if (i0 + 2 < n) { rowptr[i0 + 2] = p; cursor[i0 + 2] = p; } p += v2;
        if (i0 + 3 < n) { rowptr[i0 + 3] = p; cursor[i0 + 3] = p; }
        run += total;
        __syncthreads();
    }
    if (tid == 0) rowptr[n] = run;
}

// Fill CSR buckets with edge ids (+ optionally the source node per slot)
template<bool HAS_SRCV>
__global__ void fill_kernel(const int* __restrict__ dst, const int* __restrict__ src,
                            int* __restrict__ cursor, int* __restrict__ col,
                            int* __restrict__ srcv, int E) {
    int e = blockIdx.x * blockDim.x + threadIdx.x;
    if (e < E) {
        int p = atomicAdd(&cursor[dst[e]], 1);
        col[p] = e;
        if (HAS_SRCV) srcv[p] = src[e];
    }
}

// ---------------------------------------------------------------------------
// Aggregation: one wave per node (lane = feature). Fuses edge encoder.
//   u[v][l] = (1+eps)*h[v][l] + sum_{e in CSR[v]} relu(h[src[e]][l] + emb(e,l))
template<bool HAS_SRCV>
__global__ void agg_kernel(const float* __restrict__ h, const float* __restrict__ ea,
                           const int* __restrict__ src, const int* __restrict__ rowptr,
                           const int* __restrict__ col, const int* __restrict__ srcv,
                           const float* __restrict__ W_edge,
                           const float* __restrict__ b_edge, const float* __restrict__ eps,
                           int layer, float* __restrict__ u, int n) {
    int v = blockIdx.x * 4 + (threadIdx.x >> 6);
    int l = threadIdx.x & 63;
    if (v >= n) return;
    float w[7];
#pragma unroll
    for (int k = 0; k < 7; ++k) w[k] = W_edge[k * DD + l];
    float be = b_edge[l];
    float acc = 0.f;
    int beg = rowptr[v], end = rowptr[v + 1];
    int e = 0, s = 0;
    if (beg < end) {
        e = col[beg];
        s = HAS_SRCV ? srcv[beg] : src[e];
    }
    for (int idx = beg; idx < end; ++idx) {
        // prefetch next edge's indices so they overlap this edge's body loads
        int e_n = 0, s_n = 0;
        if (idx + 1 < end) {
            e_n = col[idx + 1];
            s_n = HAS_SRCV ? srcv[idx + 1] : src[e_n];
        }
        float hv = h[(size_t)s * DD + l];
        const float* eap = ea + (size_t)e * 7;
        float emb = be;
#pragma unroll
        for (int k = 0; k < 7; ++k) emb += eap[k] * w[k];
        float m = hv + emb;
        acc += (m > 0.f) ? m : 0.f;
        e = e_n; s = s_n;
    }
    float ope = 1.0f + eps[layer];
    u[(size_t)v * DD + l] = ope * h[(size_t)v * DD + l] + acc;
}

// ---------------------------------------------------------------------------
// MLP: h_out = relu(u @ W + b), tiled 64 nodes/block, W in LDS.
__global__ void mlp_kernel(const float* __restrict__ u, const float* __restrict__ W,
                           const float* __restrict__ b, float* __restrict__ h_out, int n) {
    __shared__ float uS[64][DD];
    __shared__ float wS[DD][DD];
    int tid = threadIdx.x;            // 256
    int nodeBase = blockIdx.x * 64;
    for (int i = tid; i < DD * DD; i += 256) wS[i >> 6][i & 63] = W[i];
    for (int i = tid; i < 64 * DD; i += 256) {
        int node = nodeBase + (i >> 6);
        uS[i >> 6][i & 63] = (node < n) ? u[(size_t)node * DD + (i & 63)] : 0.f;
    }
    __syncthreads();
    int j = tid & 63;
    int g = tid >> 6;                 // 0..3, each handles 16 nodes
    float bj = b[j];
    for (int nn = g * 16; nn < g * 16 + 16; ++nn) {
        float acc = bj;
#pragma unroll 8
        for (int l = 0; l < DD; ++l) acc += uS[nn][l] * wS[l][j];
        int node = nodeBase + nn;
        if (node < n) h_out[(size_t)node * DD + j] = (acc > 0.f) ? acc : 0.f;
    }
}

// ---------------------------------------------------------------------------
// Per-layer mean-pool partial: batch is sorted, one atomic per graph transition.
__global__ void pool_kernel(const float* __restrict__ h, const int* __restrict__ batch,
                            float* __restrict__ g_sum, int layer, int n) {
    int wave = (blockIdx.x * blockDim.x + threadIdx.x) >> 6;
    int l = threadIdx.x & 63;
    int v0 = wave * 64;
    if (v0 >= n) return;
    int vend = min(v0 + 64, n);
    int cur = batch[v0];
    float acc = 0.f;
    for (int v = v0; v < vend; ++v) {
        int bv = batch[v];
        if (bv != cur) {
            atomicAdd(&g_sum[cur * LD + layer * DD + l], acc);
            acc = 0.f;
            cur = bv;
        }
        acc += h[(size_t)v * DD + l];
    }
    atomicAdd(&g_sum[cur * LD + layer * DD + l], acc);
}

// Per-graph node counts via binary search over the SORTED batch array.
// One thread per graph: cnt[g] = lower_bound(g+1) - lower_bound(g).
__global__ void graph_cnt_kernel(const int* __restrict__ batch, int* __restrict__ cnt,
                                 int n, int G) {
    int g = blockIdx.x * blockDim.x + threadIdx.x;
    if (g >= G) return;
    // lower_bound for value g
    int lo = 0, hi = n;
    while (lo < hi) { int mid = (lo + hi) >> 1; if (batch[mid] < g) lo = mid + 1; else hi = mid; }
    int lb0 = lo;
    lo = lb0; hi = n;
    while (lo < hi) { int mid = (lo + hi) >> 1; if (batch[mid] < g + 1) lo = mid + 1; else hi = mid; }
    cnt[g] = lo - lb0;
}

// Readout: out[g][t] = b_pred[t] + sum_k (g_sum[g][k]/max(cnt,1)) * W_pred[k][t]
__global__ void readout_kernel(const float* __restrict__ g_sum, const int* __restrict__ cnt,
                               const float* __restrict__ W_pred, const float* __restrict__ b_pred,
                               float* __restrict__ out, int G) {
    int id = blockIdx.x * blockDim.x + threadIdx.x;
    if (id >= G * NT) return;
    int g = id / NT, t = id % NT;
    float c = (float)cnt[g];
    if (c < 1.f) c = 1.f;
    float inv = 1.f / c;
    float acc = b_pred[t];
    const float* gs = g_sum + g * LD;
    for (int k = 0; k < LD; ++k) acc += gs[k] * inv * W_pred[k * NT + t];
    out[id] = acc;
}

// ---------------------------------------------------------------------------
extern "C" void kernel_launch(void* const* d_in, const int* in_sizes, int n_in,
                              void* d_out, int out_size, void* d_ws, size_t ws_size,
                              hipStream_t stream) {
    const float* x       = (const float*)d_in[0];
    const int*   eidx    = (const int*)d_in[1];
    const float* ea      = (const float*)d_in[2];
    const int*   batch   = (const int*)d_in[3];
    const float* W_edge  = (const float*)d_in[4];
    const float* b_edge  = (const float*)d_in[5];
    const float* eps     = (const float*)d_in[6];
    const float* W_mlp   = (const float*)d_in[7];
    const float* b_mlp   = (const float*)d_in[8];
    const float* W_pred  = (const float*)d_in[9];
    const float* b_pred  = (const float*)d_in[10];
    float* out = (float*)d_out;

    const int N = in_sizes[3];          // 100000
    const int E = in_sizes[2] / 7;      // 1250000
    const int G = out_size / NT;        // 128
    const int* src = eidx;              // edge_index[0]
    const int* dst = eidx + E;          // edge_index[1]

    // workspace layout
    char* w0 = (char*)d_ws;
    char* w = w0;
    float* u      = (float*)w;                 w += (size_t)N * DD * 4;
    float* hA     = (float*)w;                 w += (size_t)N * DD * 4;
    int*   deg    = (int*)w;                   w += (size_t)N * 4;
    int*   rowptr = (int*)w;                   w += (size_t)(N + 1) * 4;
    int*   cursor = (int*)w;                   w += (size_t)N * 4;
    int*   col    = (int*)w;                   w += (size_t)E * 4;
    float* g_sum  = (float*)w;                 w += (size_t)G * LD * 4;
    int*   cnt    = (int*)w;                   w += (size_t)G * 4;
    // optional srcv (source node per CSR slot) if workspace allows
    size_t used = (size_t)(w - w0);
    int* srcv = nullptr;
    if (ws_size >= used + (size_t)E * 4) { srcv = (int*)w; }

    hipMemsetAsync(deg, 0, (size_t)N * 4, stream);
    hipMemsetAsync(g_sum, 0, (size_t)G * LD * 4, stream);

    // CSR build (once per launch; shared by all 5 layers)
    deg_kernel<<<(E + 255) / 256, 256, 0, stream>>>(dst, deg, E);
    scan_kernel<<<1, 1024, 0, stream>>>(deg, rowptr, cursor, N);
    if (srcv)
        fill_kernel<true><<<(E + 255) / 256, 256, 0, stream>>>(dst, src, cursor, col, srcv, E);
    else
        fill_kernel<false><<<(E + 255) / 256, 256, 0, stream>>>(dst, src, cursor, col, srcv, E);

    graph_cnt_kernel<<<(G + 127) / 128, 128, 0, stream>>>(batch, cnt, N, G);

    const float* h_cur = x;
    int aggBlocks  = (N + 3) / 4;
    int mlpBlocks  = (N + 63) / 64;
    int poolThreads = ((N + 63) / 64) * 64;
    int poolBlocks = (poolThreads + 255) / 256;
    for (int i = 0; i < NL; ++i) {
        if (srcv)
            agg_kernel<true><<<aggBlocks, 256, 0, stream>>>(h_cur, ea, src, rowptr, col, srcv,
                                                            W_edge, b_edge, eps, i, u, N);
        else
            agg_kernel<false><<<aggBlocks, 256, 0, stream>>>(h_cur, ea, src, rowptr, col, srcv,
                                                             W_edge, b_edge, eps, i, u, N);
        mlp_kernel<<<mlpBlocks, 256, 0, stream>>>(u, W_mlp + (size_t)i * DD * DD,
                                                  b_mlp + (size_t)i * DD, hA, N);
        pool_kernel<<<poolBlocks, 256, 0, stream>>>(hA, batch, g_sum, i, N);
        h_cur = hA;
    }

    readout_kernel<<<(G * NT + 255) / 256, 256, 0, stream>>>(g_sum, cnt, W_pred, b_pred, out, G);
}